// Round 8
// baseline (584.030 us; speedup 1.0000x reference)
//
#include <hip/hip_runtime.h>
#include <hip/hip_bf16.h>
#include <math.h>

#define NN 8192
#define FF 64
#define HH 128
#define RR 3
#define DEG 32
#define KK 32
#define EE (NN*DEG)
#define DD 131            // 2F+3
#define TEMP 0.3f
#define NEG_SLOPE 0.2f
#define EPS_LN 1e-5f
#define W_THRESH 1e-6f

typedef float v2f __attribute__((ext_vector_type(2)));
__device__ __forceinline__ float4 ld4(const float* p) { return *(const float4*)p; }
#define PKFMA(a, b, c) __builtin_elementwise_fma((a), (b), (c))
// scalar view of packed accumulator: element j (0..15) of the old float[16]
#define AIDX(a, j) a[((j)>>2)*2 + (((j)&3)>>1)][(j)&1]
#define GIDX(r, g) gaccv[r][(g)>>1][(g)&1]

// ws layout (floats):
//  [0..127]   hdr: [0]=contagion_sum [1..3]=regime_probs [4]=amp [8..71]=colsum
//  [128 .. 128+EE)  edge scores
//  [tabs ..)  PA1, PA2 prefix tables
//
// INVARIANT (R15): per-edge score arithmetic must replicate the reference's
// ascending-k FMA chain BITWISE; LN/Ws2 lane mapping + reduction order is
// proven-passing and must not change.
// R17 (banked): LDS-staged W panels + T14 async prefetch -> 308.6us edge.
// R18 (failed): W direct-from-L2 exposes latency. R20 (null): compiler had
// already unrolled. R21 (failed, 425us): 4edge x 8col reshard -> w-reads
// became 4-way bank-conflicted (conflicts 1.0e7->2.9e7). LESSON: R17's
// w-reads are same-address broadcasts across trow groups (conflict-free);
// LDS cost is per-instruction distinct-address bank-cycles, NOT bytes/69TBs.
// R17 LDS pipe ~20-25% of cycles; kernel ~46% of FP32 vector peak on FMAs.
// R22 (this round): R20 kernel + double-buffered WPan[2]/WgPan[2] panels:
// write panel p+1 into the idle buffer before computing p -> 1 barrier per
// panel (36 -> 22 barriers/block). Staged values, FMA chains, lane mappings
// bit-identical. Also dual-GEMM a-reads widened 4xb32 -> 1xb128 (EIr rows
// k-contiguous; ascending-k use order preserved). LDS 32.3->44.3KB, cap 3
// blocks/CU = 12 waves > measured ~10.4 resident (R18: occupancy LDS-insensitive).
// NOTE (R7/R8): no second __launch_bounds__ arg — collapses VGPR, spills.
// NOTE (R10): v_pk_fma_f32 — each component is an exact IEEE FMA.
// NOTE (R11): 512-thr/128-edge blocks regress; 256-thr/64-edge is the sweet spot.
// NOTE (R12/R19): standalone finalize; non-edge residual has ±20us run noise.
// NOTE (R14): keep regime as a standalone dispatch.

// ---------------- Setup kernel: blocks 0..1023 = prefix tables (col-halved), 1024..1151 = stats ----------------
__global__ __launch_bounds__(256) void setup_kernel(
    const float* __restrict__ x,
    const float* __restrict__ Ws1, const float* __restrict__ Wp,
    const float* __restrict__ Wc1, const float* __restrict__ bc1,
    const float* __restrict__ Wc2, const float* __restrict__ bc2,
    float* __restrict__ PA, float* __restrict__ hdr)
{
    __shared__ float spool[12608];
    int t = threadIdx.x;
    int bid = blockIdx.x;

    if (bid < 1024) {
        float* xs = spool;          // [32][65]
        float* wl = spool + 2080;   // [64][64]
        int which = bid & 1;
        int ch    = (bid >> 1) & 1;   // column half
        int n0    = (bid >> 2) * 32;
        const float* base = which ? Wp : Ws1;

        for (int i = t; i < 2048; i += 256)
            xs[(i >> 6) * 65 + (i & 63)] = x[n0 * 64 + i];
        for (int it = 0; it < 4; it++) {
            int flat = (t + it * 256) * 4;     // 0..4092
            int r = flat >> 6, c = flat & 63;
            *(float4*)&wl[flat] = ld4(&base[r * 128 + ch * 64 + c]);
        }
        __syncthreads();

        int row = t >> 3, colg = t & 7;        // 32 rows x 8 col-groups
        float acc[8];
        #pragma unroll
        for (int j = 0; j < 8; j++) acc[j] = 0.f;
        const float* xr = &xs[row * 65];
        for (int k = 0; k < 64; k++) {
            float a = xr[k];
            const float* wr = &wl[k * 64 + colg * 8];
            #pragma unroll
            for (int jj = 0; jj < 2; jj++) {
                float4 w = ld4(wr + 4 * jj);
                acc[4*jj+0] += a * w.x; acc[4*jj+1] += a * w.y;
                acc[4*jj+2] += a * w.z; acc[4*jj+3] += a * w.w;
            }
        }
        float* outp = PA + (size_t)which * (NN * 128) + (size_t)(n0 + row) * 128 + ch * 64 + colg * 8;
        #pragma unroll
        for (int j = 0; j < 8; j++) outp[j] = acc[j];
    } else {
        float* xs = spool;          // [64][65]
        float* wl = spool + 4160;   // [64][128]
        float* cs = spool + 12352;  // [4][64]
        int n0 = (bid - 1024) * 64;

        for (int i = 0; i < 16; i++) {
            int flat = t + i * 256;
            int r = flat >> 6, c = flat & 63;
            xs[r * 65 + c] = x[(n0 + r) * 64 + c];
        }
        for (int i = 0; i < 8; i++) {
            int flat = (t + i * 256) * 4;
            *(float4*)&wl[flat] = ld4(&Wc1[flat]);
        }
        __syncthreads();

        {
            int col = t & 63, g = t >> 6;
            float ps = 0.f;
            for (int r = g * 16; r < g * 16 + 16; r++) ps += xs[r * 65 + col];
            cs[g * 64 + col] = ps;
        }
        __syncthreads();
        if (t < 64) {
            float v = cs[t] + cs[64 + t] + cs[128 + t] + cs[192 + t];
            atomicAdd(&hdr[8 + t], v);
        }

        int r = t >> 2, q = t & 3;
        float accl = 0.f;
        for (int hh = 0; hh < 32; hh++) {
            int h = hh * 4 + q;
            float s = bc1[h];
            for (int i = 0; i < 64; i++) s += xs[r * 65 + i] * wl[i * 128 + h];
            accl += fmaxf(s, 0.f) * Wc2[h];
        }
        accl += __shfl_xor(accl, 1);
        accl += __shfl_xor(accl, 2);
        if (q == 0) {
            float lvl = 1.f / (1.f + expf(-(accl + bc2[0])));
            atomicAdd(&hdr[0], lvl);
        }
    }
}

// ---------------- Kernel B: regime probs + amp ----------------
__global__ __launch_bounds__(128) void regime_kernel(
    const float* __restrict__ Wr1, const float* __restrict__ br1,
    const float* __restrict__ Wr2, const float* __restrict__ br2,
    float* __restrict__ hdr)
{
    __shared__ float gsl[64];
    __shared__ float t1[128];
    int t = threadIdx.x;
    if (t < 64) gsl[t] = hdr[8 + t] * (1.f / (float)NN);
    __syncthreads();
    float a = br1[t];
    for (int i = 0; i < 64; i++) a += gsl[i] * Wr1[i * 128 + t];
    t1[t] = fmaxf(a, 0.f);
    __syncthreads();
    if (t < 3) {
        float v = br2[t];
        for (int h = 0; h < 128; h++) v += t1[h] * Wr2[h * 3 + t];
        gsl[32 + t] = v;
    }
    __syncthreads();
    if (t == 0) {
        float v0 = gsl[32], v1 = gsl[33], v2 = gsl[34];
        float m = fmaxf(v0, fmaxf(v1, v2));
        float e0 = expf(v0 - m), e1 = expf(v1 - m), e2 = expf(v2 - m);
        float inv = 1.f / (e0 + e1 + e2);
        hdr[1] = e0 * inv; hdr[2] = e1 * inv; hdr[3] = e2 * inv;
        hdr[4] = 1.f + 0.5f * (hdr[0] * (1.f / (float)NN));
    }
}

// ---------------- Fused edge kernel: R17 arithmetic + double-buffered panels ----------------
// LDS pool (floats), 11072 fl = 44288 B:
//   phase A: EIB[64][76] @0 (4864), WPan[2][2][12][128] @4864 (6144) -> 11008
//   phase B: ehTh[64][68] @0 (4352), WgPan[2][3][16][64] @4864 (6144)
//   phase C: Gbuf[64][68] @0
//   persistent: rawS @11008 (64)
#define EIB_S 76
__global__ __launch_bounds__(256) void edge_fused_kernel(
    const int* __restrict__ tgt_idx, const float* __restrict__ edge_attr,
    const float* __restrict__ x,
    const float* __restrict__ Ws1, const float* __restrict__ bs1,
    const float* __restrict__ ln_g, const float* __restrict__ ln_b,
    const float* __restrict__ Ws2, const float* __restrict__ bs2,
    const float* __restrict__ Wp, const float* __restrict__ bp,
    const float* __restrict__ Wg1, const float* __restrict__ bg1,
    const float* __restrict__ Wg2, const float* __restrict__ bg2,
    const float* __restrict__ PA1, const float* __restrict__ PA2,
    const float* __restrict__ hdr, float* __restrict__ scores)
{
    __shared__ float pool[11072];
    float* EIB   = pool;            // [64][76]
    float* WPan  = pool + 4864;     // [2 buf][2 mat][12][128]
    float* ehTh  = pool;            // [64 k-local][68] (aliases EIB)
    float* WgPan = pool + 4864;     // [2 buf][3][16][64] (aliases WPan)
    float* Gbuf  = pool;            // [64 m][68]
    float* rawS  = pool + 11008;    // [64]

    int t = threadIdx.x;
    int e0 = blockIdx.x * 64;

    // ---- stage shifted edge input: local col ii <-> original k = 64+ii ----
    {
        int r = t >> 2, q = t & 3;
        int ge = e0 + r;
        int tg = tgt_idx[ge];
        #pragma unroll
        for (int i = 0; i < 4; i++) {
            int col = q * 16 + 4 * i;
            *(float4*)&EIB[r * EIB_S + col] = ld4(&x[tg * 64 + col]);
        }
        if (q == 0) {
            float4 v;
            v.x = edge_attr[(size_t)ge * 3 + 0];
            v.y = edge_attr[(size_t)ge * 3 + 1];
            v.z = edge_attr[(size_t)ge * 3 + 2];
            v.w = 0.f;
            *(float4*)&EIB[r * EIB_S + 64] = v;
        } else if (q == 1) {
            *(float4*)&EIB[r * EIB_S + 68] = make_float4(0.f, 0.f, 0.f, 0.f);
        } else if (q == 2) {
            *(float4*)&EIB[r * EIB_S + 72] = make_float4(0.f, 0.f, 0.f, 0.f);
        }
    }

    // ---- per-thread staging descriptors (t-only; hoisted out of the loops) ----
    int spr0, spc0, sdst0, spr1, spc1, sdst1, spr2, spc2, sdst2;
    const float *ssrc0, *ssrc1, *ssrc2;
    {
        int fid, mat, loc;
        fid = t;            mat = (fid >= 384) ? 1 : 0; loc = fid - mat * 384;
        spr0 = loc >> 5; spc0 = (loc & 31) * 4; sdst0 = mat * 1536 + spr0 * 128 + spc0;
        ssrc0 = mat ? Wp : Ws1;
        fid = 256 + t;      mat = (fid >= 384) ? 1 : 0; loc = fid - mat * 384;
        spr1 = loc >> 5; spc1 = (loc & 31) * 4; sdst1 = mat * 1536 + spr1 * 128 + spc1;
        ssrc1 = mat ? Wp : Ws1;
        fid = 512 + t;      mat = (fid >= 384) ? 1 : 0; loc = fid - mat * 384;
        spr2 = loc >> 5; spc2 = (loc & 31) * 4; sdst2 = mat * 1536 + spr2 * 128 + spc2;
        ssrc2 = mat ? Wp : Ws1;
    }
    int gdst0, gdst1, gdst2, goff0, goff1, goff2;
    {
        int fid, rr, loc, pr, pc;
        fid = t;        rr = fid >> 8; loc = fid & 255; pr = loc >> 4; pc = (loc & 15) * 4;
        gdst0 = rr * 1024 + pr * 64 + pc; goff0 = rr * 8192 + pr * 64 + pc;
        fid = 256 + t;  rr = fid >> 8; loc = fid & 255; pr = loc >> 4; pc = (loc & 15) * 4;
        gdst1 = rr * 1024 + pr * 64 + pc; goff1 = rr * 8192 + pr * 64 + pc;
        fid = 512 + t;  rr = fid >> 8; loc = fid & 255; pr = loc >> 4; pc = (loc & 15) * 4;
        gdst2 = rr * 1024 + pr * 64 + pc; goff2 = rr * 8192 + pr * 64 + pc;
    }

    #define LOADP(pp, w0_, w1_, w2_)                                          \
      { int _pr0 = 64 + (pp) * 12 + spr0;                                     \
        int _pr1 = 64 + (pp) * 12 + spr1;                                     \
        int _pr2 = 64 + (pp) * 12 + spr2;                                     \
        w0_ = (_pr0 < 131) ? ld4(&ssrc0[_pr0 * 128 + spc0]) : make_float4(0.f,0.f,0.f,0.f); \
        w1_ = (_pr1 < 131) ? ld4(&ssrc1[_pr1 * 128 + spc1]) : make_float4(0.f,0.f,0.f,0.f); \
        w2_ = (_pr2 < 131) ? ld4(&ssrc2[_pr2 * 128 + spc2]) : make_float4(0.f,0.f,0.f,0.f); }

    #define LOADG(gi_, g0_, g1_, g2_)                                         \
      { g0_ = ld4(&Wg1[goff0 + (gi_) * 1024]);                                \
        g1_ = ld4(&Wg1[goff1 + (gi_) * 1024]);                                \
        g2_ = ld4(&Wg1[goff2 + (gi_) * 1024]); }

    int tcol = t & 7, trow = t >> 3;   // scalar col j: tcol*4 + (j>>2)*32 + (j&3); rows 2*trow,2*trow+1
    const float* EIr0 = &EIB[(2 * trow) * EIB_S];
    const float* EIr1 = EIr0 + EIB_S;
    int src = (e0 + 2 * trow) >> 5;

    v2f accs0[8], accs1[8], accp0[8], accp1[8];

    // ---- init accumulators from prefix tables (exact chain state after k=63) ----
    {
        const float* p1 = &PA1[(size_t)src * 128 + tcol * 4];
        const float* p2 = &PA2[(size_t)src * 128 + tcol * 4];
        #pragma unroll
        for (int jj = 0; jj < 4; jj++) {
            float4 v;
            v = ld4(p1 + jj * 32);
            v2f lo1 = { v.x, v.y }, hi1 = { v.z, v.w };
            accs0[jj*2] = lo1; accs0[jj*2+1] = hi1;
            accs1[jj*2] = lo1; accs1[jj*2+1] = hi1;
            v = ld4(p2 + jj * 32);
            v2f lo2 = { v.x, v.y }, hi2 = { v.z, v.w };
            accp0[jj*2] = lo2; accp0[jj*2+1] = hi2;
            accp1[jj*2] = lo2; accp1[jj*2+1] = hi2;
        }
    }

    // ---- fused dual-GEMM k-loop: 6 panels x 12 rows, double-buffered WPan ----
    float4 wra, wrb, wrc;
    LOADP(0, wra, wrb, wrc);
    // write panel 0 into buf0 (no prior readers)
    *(float4*)&WPan[sdst0] = wra;
    *(float4*)&WPan[sdst1] = wrb;
    *(float4*)&WPan[sdst2] = wrc;
    LOADP(1, wra, wrb, wrc);
    __syncthreads();                           // EIB + WPan buf0 visible
    for (int p = 0; p < 6; p++) {
        int bufo = (p & 1) * 3072;
        if (p < 5) {
            // write panel p+1 into the idle buffer (its readers done at prior barrier)
            int nbufo = ((p + 1) & 1) * 3072;
            *(float4*)&WPan[nbufo + sdst0] = wra;
            *(float4*)&WPan[nbufo + sdst1] = wrb;
            *(float4*)&WPan[nbufo + sdst2] = wrc;
            if (p < 4) LOADP(p + 2, wra, wrb, wrc);
        }
        #pragma unroll
        for (int kt = 0; kt < 3; kt++) {
            float4 aq0 = ld4(&EIr0[p * 12 + kt * 4]);   // 4 k-values, contiguous
            float4 aq1 = ld4(&EIr1[p * 12 + kt * 4]);
            float a0s[4] = { aq0.x, aq0.y, aq0.z, aq0.w };
            float a1s[4] = { aq1.x, aq1.y, aq1.z, aq1.w };
            #pragma unroll
            for (int kk2 = 0; kk2 < 4; kk2++) {
                int kk = kt * 4 + kk2;
                v2f a0v = { a0s[kk2], a0s[kk2] }, a1v = { a1s[kk2], a1s[kk2] };
                const float* ws = &WPan[bufo + kk * 128 + tcol * 4];
                const float* wq = ws + 1536;
                #pragma unroll
                for (int jj = 0; jj < 4; jj++) {
                    float4 w1 = ld4(ws + jj * 32);
                    v2f w1a = { w1.x, w1.y }, w1b = { w1.z, w1.w };
                    accs0[jj*2]   = PKFMA(a0v, w1a, accs0[jj*2]);
                    accs0[jj*2+1] = PKFMA(a0v, w1b, accs0[jj*2+1]);
                    accs1[jj*2]   = PKFMA(a1v, w1a, accs1[jj*2]);
                    accs1[jj*2+1] = PKFMA(a1v, w1b, accs1[jj*2+1]);
                    float4 w2 = ld4(wq + jj * 32);
                    v2f w2a = { w2.x, w2.y }, w2b = { w2.z, w2.w };
                    accp0[jj*2]   = PKFMA(a0v, w2a, accp0[jj*2]);
                    accp0[jj*2+1] = PKFMA(a0v, w2b, accp0[jj*2+1]);
                    accp1[jj*2]   = PKFMA(a1v, w2a, accp1[jj*2]);
                    accp1[jj*2+1] = PKFMA(a1v, w2b, accp1[jj*2+1]);
                }
            }
        }
        if (p < 5) __syncthreads();            // panel p+1 writes visible / p reads done
    }

    // ---- prefetch first gating panel; lands under LN phase ----
    float4 gra, grb, grc;
    LOADG(0, gra, grb, grc);

    // ---- +bias, LayerNorm, LeakyReLU, dot Ws2 (verbatim scalar chains) ----
    {
        float s0 = 0.f, ss0 = 0.f, s1 = 0.f, ss1 = 0.f;
        #pragma unroll
        for (int j = 0; j < 16; j++) {
            int col = tcol * 4 + (j >> 2) * 32 + (j & 3);
            float b = bs1[col];
            float u0 = AIDX(accs0, j) + b;  AIDX(accs0, j) = u0;
            float u1 = AIDX(accs1, j) + b;  AIDX(accs1, j) = u1;
            s0 += u0; ss0 += u0 * u0;
            s1 += u1; ss1 += u1 * u1;
        }
        #pragma unroll
        for (int m = 1; m < 8; m <<= 1) {
            s0 += __shfl_xor(s0, m);  ss0 += __shfl_xor(ss0, m);
            s1 += __shfl_xor(s1, m);  ss1 += __shfl_xor(ss1, m);
        }
        float mu0 = s0 * (1.f / 128.f), mu1 = s1 * (1.f / 128.f);
        float var0 = ss0 * (1.f / 128.f) - mu0 * mu0;
        float var1 = ss1 * (1.f / 128.f) - mu1 * mu1;
        float inv0 = 1.f / sqrtf(var0 + EPS_LN);
        float inv1 = 1.f / sqrtf(var1 + EPS_LN);
        float d0 = 0.f, d1 = 0.f;
        #pragma unroll
        for (int j = 0; j < 16; j++) {
            int col = tcol * 4 + (j >> 2) * 32 + (j & 3);
            float g = ln_g[col], bb = ln_b[col], w2 = Ws2[col];
            float y0 = (AIDX(accs0, j) - mu0) * inv0 * g + bb;
            float y1 = (AIDX(accs1, j) - mu1) * inv1 * g + bb;
            y0 = (y0 >= 0.f) ? y0 : NEG_SLOPE * y0;
            y1 = (y1 >= 0.f) ? y1 : NEG_SLOPE * y1;
            d0 += y0 * w2; d1 += y1 * w2;
        }
        #pragma unroll
        for (int m = 1; m < 8; m <<= 1) {
            d0 += __shfl_xor(d0, m); d1 += __shfl_xor(d1, m);
        }
        if (tcol == 0) {
            rawS[2 * trow]     = d0 + bs2[0];
            rawS[2 * trow + 1] = d1 + bs2[0];
        }
    }

    // ================= gating: two 64-k halves, double-buffered WgPan =================
    int gtr = t >> 4, gtc = t & 15;            // edges 4*gtr+i ; m 4*gtc+j
    int grow = t >> 2, gq = t & 3;             // p-phase mapping (R1 chain)

    v2f gaccv[3][8];
    #pragma unroll
    for (int rr = 0; rr < 3; rr++)
        #pragma unroll
        for (int j = 0; j < 8; j++) gaccv[rr][j] = (v2f){ 0.f, 0.f };

    for (int hf = 0; hf < 2; hf++) {
        __syncthreads();                       // EIB/WPan reads done (hf=0) / gi3 compute + ehTh reads done (hf=1)
        #pragma unroll
        for (int j2 = 0; j2 < 8; j2++) {
            int j = hf * 8 + j2;
            int col = tcol * 4 + (j >> 2) * 32 + (j & 3);
            int lc = col - hf * 64;            // 0..63
            float b = bp[col];
            ehTh[lc * 68 + 2 * trow]     = fmaxf(AIDX(accp0, j) + b, 0.f);
            ehTh[lc * 68 + 2 * trow + 1] = fmaxf(AIDX(accp1, j) + b, 0.f);
        }
        // write this half's first panel into buf0 (its readers done 2 barriers ago)
        *(float4*)&WgPan[gdst0] = gra;
        *(float4*)&WgPan[gdst1] = grb;
        *(float4*)&WgPan[gdst2] = grc;
        LOADG(hf * 4 + 1, gra, grb, grc);
        __syncthreads();                       // ehTh half + WgPan buf0 visible
        for (int p = 0; p < 4; p++) {
            int gbufo = (p & 1) * 3072;
            if (p < 3) {
                int ngbufo = ((p + 1) & 1) * 3072;
                *(float4*)&WgPan[ngbufo + gdst0] = gra;
                *(float4*)&WgPan[ngbufo + gdst1] = grb;
                *(float4*)&WgPan[ngbufo + gdst2] = grc;
                int gi = hf * 4 + p;
                if (gi + 2 <= 7) LOADG(gi + 2, gra, grb, grc);
            }
            #pragma unroll
            for (int kk = 0; kk < 16; kk++) {
                float4 av = ld4(&ehTh[(p * 16 + kk) * 68 + 4 * gtr]);
                v2f ax = { av.x, av.x }, ay = { av.y, av.y };
                v2f az = { av.z, av.z }, aw = { av.w, av.w };
                #pragma unroll
                for (int rr = 0; rr < 3; rr++) {
                    float4 bv = ld4(&WgPan[gbufo + rr * 1024 + kk * 64 + 4 * gtc]);
                    v2f bva = { bv.x, bv.y }, bvb = { bv.z, bv.w };
                    gaccv[rr][0] = PKFMA(ax, bva, gaccv[rr][0]);
                    gaccv[rr][1] = PKFMA(ax, bvb, gaccv[rr][1]);
                    gaccv[rr][2] = PKFMA(ay, bva, gaccv[rr][2]);
                    gaccv[rr][3] = PKFMA(ay, bvb, gaccv[rr][3]);
                    gaccv[rr][4] = PKFMA(az, bva, gaccv[rr][4]);
                    gaccv[rr][5] = PKFMA(az, bvb, gaccv[rr][5]);
                    gaccv[rr][6] = PKFMA(aw, bva, gaccv[rr][6]);
                    gaccv[rr][7] = PKFMA(aw, bvb, gaccv[rr][7]);
                }
            }
            if (p < 3) __syncthreads();        // next panel visible / this panel reads done
        }
    }

    // ---- Gbuf + p-phase per regime (R1 lane mapping / add order) ----
    float gc = 0.f;
    for (int rr = 0; rr < 3; rr++) {
        __syncthreads();                       // ehTh k-loop reads (rr==0) / prior p-phase reads done
        #pragma unroll
        for (int j = 0; j < 4; j++) {
            float b = bg1[rr * 64 + 4 * gtc + j];
            float4 g;
            g.x = fmaxf(GIDX(rr, 0  + j) + b, 0.f);
            g.y = fmaxf(GIDX(rr, 4  + j) + b, 0.f);
            g.z = fmaxf(GIDX(rr, 8  + j) + b, 0.f);
            g.w = fmaxf(GIDX(rr, 12 + j) + b, 0.f);
            *(float4*)&Gbuf[(4 * gtc + j) * 68 + 4 * gtr] = g;
        }
        __syncthreads();
        float pacc = 0.f;
        #pragma unroll
        for (int j = 0; j < 16; j++) {
            int m = gq * 4 + (j >> 2) * 16 + (j & 3);
            pacc += Gbuf[m * 68 + grow] * Wg2[rr * 64 + m];
        }
        pacc += __shfl_xor(pacc, 1);
        pacc += __shfl_xor(pacc, 2);
        float gate = 1.f / (1.f + expf(-(pacc + bg2[rr])));
        gc += gate * hdr[1 + rr];
    }
    if (gq == 0) scores[e0 + grow] = rawS[grow] * gc * hdr[4];
}

// ---------------- Kernel D: dedup + softmax + stable top-k, 2 rows per block ----------------
__global__ __launch_bounds__(64) void finalize_kernel(
    const int* __restrict__ tgt_idx, const float* __restrict__ scores,
    float* __restrict__ out_w, float* __restrict__ out_i)
{
    __shared__ int   tl[64];
    __shared__ float pl[64];
    int j = threadIdx.x;
    int half = j >> 5;
    int jl = j & 31;
    int hb = half * 32;
    int row = blockIdx.x * 2 + half;
    int   tg = tgt_idx[row * 32 + jl];
    float s  = scores[row * 32 + jl];
    tl[j] = tg;
    __syncthreads();

    bool alive = true;
    for (int j2 = jl + 1; j2 < 32; j2++)
        if (tl[hb + j2] == tg) { alive = false; break; }
    float z = alive ? s * (1.f / TEMP) : -INFINITY;
    float m = z;
    #pragma unroll
    for (int mm = 1; mm < 32; mm <<= 1) m = fmaxf(m, __shfl_xor(m, mm));
    float p = alive ? expf(z - m) : 0.f;
    float sum = p;
    #pragma unroll
    for (int mm = 1; mm < 32; mm <<= 1) sum += __shfl_xor(sum, mm);
    p = p / sum;
    pl[j] = alive ? p : -1.f;
    __syncthreads();

    int rank = 0, dcount = 0;
    for (int j2 = 0; j2 < 32; j2++) {
        float pj = pl[hb + j2];
        if (pj >= 0.f) {
            dcount++;
            if (alive) {
                if (pj > p || (pj == p && tl[hb + j2] < tg)) rank++;
            }
        }
    }
    if (alive) {
        out_w[row * 32 + rank] = (p > W_THRESH) ? p : 0.f;
        out_i[row * 32 + rank] = (float)tg;
    }
    if (jl == 0) {
        int c = 0;
        for (int slot = dcount; slot < 32; slot++) {
            for (;;) {
                bool found = false;
                for (int q = 0; q < 32; q++) if (tl[hb + q] == c) { found = true; break; }
                if (!found) break;
                c++;
            }
            out_w[row * 32 + slot] = 0.f;
            out_i[row * 32 + slot] = (float)c;
            c++;
        }
    }
}

extern "C" void kernel_launch(void* const* d_in, const int* in_sizes, int n_in,
                              void* d_out, int out_size, void* d_ws, size_t ws_size,
                              hipStream_t stream)
{
    const float* x          = (const float*)d_in[0];
    const int*   edge_index = (const int*)  d_in[1];
    const float* edge_attr  = (const float*)d_in[2];
    const float* Ws1 = (const float*)d_in[3];
    const float* bs1 = (const float*)d_in[4];
    const float* ln_g = (const float*)d_in[5];
    const float* ln_b = (const float*)d_in[6];
    const float* Ws2 = (const float*)d_in[7];
    const float* bs2 = (const float*)d_in[8];
    const float* Wp  = (const float*)d_in[9];
    const float* bp  = (const float*)d_in[10];
    const float* Wr1 = (const float*)d_in[11];
    const float* br1 = (const float*)d_in[12];
    const float* Wr2 = (const float*)d_in[13];
    const float* br2 = (const float*)d_in[14];
    const float* Wg1 = (const float*)d_in[15];
    const float* bg1 = (const float*)d_in[16];
    const float* Wg2 = (const float*)d_in[17];
    const float* bg2 = (const float*)d_in[18];
    const float* Wc1 = (const float*)d_in[19];
    const float* bc1 = (const float*)d_in[20];
    const float* Wc2 = (const float*)d_in[21];
    const float* bc2 = (const float*)d_in[22];

    float* hdr    = (float*)d_ws;
    float* scores = hdr + 128;
    float* tabs   = scores + EE;            // PA1, PA2
    const int* tgt = edge_index + EE;       // row 1 of edge_index

    hipMemsetAsync(d_ws, 0, 512, stream);
    setup_kernel<<<1152, 256, 0, stream>>>(x, Ws1, Wp, Wc1, bc1, Wc2, bc2, tabs, hdr);
    regime_kernel<<<1, 128, 0, stream>>>(Wr1, br1, Wr2, br2, hdr);
    edge_fused_kernel<<<EE / 64, 256, 0, stream>>>(
        tgt, edge_attr, x, Ws1, bs1, ln_g, ln_b, Ws2, bs2, Wp, bp,
        Wg1, bg1, Wg2, bg2, tabs, tabs + (size_t)NN * 128, hdr, scores);
    finalize_kernel<<<NN / 2, 64, 0, stream>>>(
        tgt, scores, (float*)d_out, (float*)d_out + NN * KK);
}

// Round 10
// 424.319 us; speedup vs baseline: 1.3764x; 1.3764x over previous
//
#include <hip/hip_runtime.h>
#include <hip/hip_bf16.h>
#include <math.h>

#define NN 8192
#define FF 64
#define HH 128
#define RR 3
#define DEG 32
#define KK 32
#define EE (NN*DEG)
#define DD 131            // 2F+3
#define TEMP 0.3f
#define NEG_SLOPE 0.2f
#define EPS_LN 1e-5f
#define W_THRESH 1e-6f

typedef float v2f __attribute__((ext_vector_type(2)));
__device__ __forceinline__ float4 ld4(const float* p) { return *(const float4*)p; }
#define PKFMA(a, b, c) __builtin_elementwise_fma((a), (b), (c))
// scalar view of packed accumulator: element j (0..15) of the old float[16]
#define AIDX(a, j) a[((j)>>2)*2 + (((j)&3)>>1)][(j)&1]
#define GIDX(r, g) gaccv[r][(g)>>1][(g)&1]

// ws layout (floats):
//  [0..127]   hdr: [0]=contagion_sum [1..3]=regime_probs [4]=amp [8..71]=colsum
//  [128 .. 128+EE)  edge scores
//  [tabs ..)  PA1, PA2 prefix tables
//
// INVARIANT (R15): per-edge score arithmetic must replicate the reference's
// ascending-k FMA chain BITWISE. Reordering (PB-table hoist, bf16/MFMA,
// cross-lane partial-sum splits) flips near-tied softmax pairs -> index errors.
// === Edge-kernel experiment ledger (all on the R17 structure, 308.6us) ===
// R18 W-direct-from-L2: 503us — exposed ~200cy load latency, VALUBusy 70->41.
// R20 inner-loop unroll pragma: null — compiler already unrolled.
// R21 4edge x 8col reshard: 425us — w-reads 4-way bank-conflicted (1e7->2.9e7).
//     LESSON: R17 w-reads are same-address broadcasts (free); LDS cost is
//     per-instruction distinct-address bank cycles, not bytes/69TBs.
// R22 double-buffered panels + wide a-reads: 493us — VGPR 84->168, occupancy
//     32->11.8%. LESSON: barrier drain is absorbed by 4-waves/SIMD cross-wave
//     overlap; explicit dbuf only adds register pressure (learn_hip m99/m100).
// R23: identical source resubmitted — R9 bench was an infra failure
//     ("container failed twice"), not a kernel signal.
// CONCLUSION: R17/R20 config is the local optimum under the bitwise-chain
// invariant: ~46% FP32 vector peak, VALUBusy ~70%, VGPR-tier-capped.
// NOTE (R7/R8): no second __launch_bounds__ arg — collapses VGPR, spills.
// NOTE (R10): v_pk_fma_f32 — each component is an exact IEEE FMA.
// NOTE (R11): 512-thr/128-edge blocks regress; 256-thr/64-edge is the sweet spot.
// NOTE (R12/R19): standalone finalize; non-edge residual has ±20us run noise.
// NOTE (R14): keep regime as a standalone dispatch.

// ---------------- Setup kernel: blocks 0..1023 = prefix tables (col-halved), 1024..1151 = stats ----------------
__global__ __launch_bounds__(256) void setup_kernel(
    const float* __restrict__ x,
    const float* __restrict__ Ws1, const float* __restrict__ Wp,
    const float* __restrict__ Wc1, const float* __restrict__ bc1,
    const float* __restrict__ Wc2, const float* __restrict__ bc2,
    float* __restrict__ PA, float* __restrict__ hdr)
{
    __shared__ float spool[12608];
    int t = threadIdx.x;
    int bid = blockIdx.x;

    if (bid < 1024) {
        float* xs = spool;          // [32][65]
        float* wl = spool + 2080;   // [64][64]
        int which = bid & 1;
        int ch    = (bid >> 1) & 1;   // column half
        int n0    = (bid >> 2) * 32;
        const float* base = which ? Wp : Ws1;

        for (int i = t; i < 2048; i += 256)
            xs[(i >> 6) * 65 + (i & 63)] = x[n0 * 64 + i];
        for (int it = 0; it < 4; it++) {
            int flat = (t + it * 256) * 4;     // 0..4092
            int r = flat >> 6, c = flat & 63;
            *(float4*)&wl[flat] = ld4(&base[r * 128 + ch * 64 + c]);
        }
        __syncthreads();

        int row = t >> 3, colg = t & 7;        // 32 rows x 8 col-groups
        float acc[8];
        #pragma unroll
        for (int j = 0; j < 8; j++) acc[j] = 0.f;
        const float* xr = &xs[row * 65];
        for (int k = 0; k < 64; k++) {
            float a = xr[k];
            const float* wr = &wl[k * 64 + colg * 8];
            #pragma unroll
            for (int jj = 0; jj < 2; jj++) {
                float4 w = ld4(wr + 4 * jj);
                acc[4*jj+0] += a * w.x; acc[4*jj+1] += a * w.y;
                acc[4*jj+2] += a * w.z; acc[4*jj+3] += a * w.w;
            }
        }
        float* outp = PA + (size_t)which * (NN * 128) + (size_t)(n0 + row) * 128 + ch * 64 + colg * 8;
        #pragma unroll
        for (int j = 0; j < 8; j++) outp[j] = acc[j];
    } else {
        float* xs = spool;          // [64][65]
        float* wl = spool + 4160;   // [64][128]
        float* cs = spool + 12352;  // [4][64]
        int n0 = (bid - 1024) * 64;

        for (int i = 0; i < 16; i++) {
            int flat = t + i * 256;
            int r = flat >> 6, c = flat & 63;
            xs[r * 65 + c] = x[(n0 + r) * 64 + c];
        }
        for (int i = 0; i < 8; i++) {
            int flat = (t + i * 256) * 4;
            *(float4*)&wl[flat] = ld4(&Wc1[flat]);
        }
        __syncthreads();

        {
            int col = t & 63, g = t >> 6;
            float ps = 0.f;
            for (int r = g * 16; r < g * 16 + 16; r++) ps += xs[r * 65 + col];
            cs[g * 64 + col] = ps;
        }
        __syncthreads();
        if (t < 64) {
            float v = cs[t] + cs[64 + t] + cs[128 + t] + cs[192 + t];
            atomicAdd(&hdr[8 + t], v);
        }

        int r = t >> 2, q = t & 3;
        float accl = 0.f;
        for (int hh = 0; hh < 32; hh++) {
            int h = hh * 4 + q;
            float s = bc1[h];
            for (int i = 0; i < 64; i++) s += xs[r * 65 + i] * wl[i * 128 + h];
            accl += fmaxf(s, 0.f) * Wc2[h];
        }
        accl += __shfl_xor(accl, 1);
        accl += __shfl_xor(accl, 2);
        if (q == 0) {
            float lvl = 1.f / (1.f + expf(-(accl + bc2[0])));
            atomicAdd(&hdr[0], lvl);
        }
    }
}

// ---------------- Kernel B: regime probs + amp ----------------
__global__ __launch_bounds__(128) void regime_kernel(
    const float* __restrict__ Wr1, const float* __restrict__ br1,
    const float* __restrict__ Wr2, const float* __restrict__ br2,
    float* __restrict__ hdr)
{
    __shared__ float gsl[64];
    __shared__ float t1[128];
    int t = threadIdx.x;
    if (t < 64) gsl[t] = hdr[8 + t] * (1.f / (float)NN);
    __syncthreads();
    float a = br1[t];
    for (int i = 0; i < 64; i++) a += gsl[i] * Wr1[i * 128 + t];
    t1[t] = fmaxf(a, 0.f);
    __syncthreads();
    if (t < 3) {
        float v = br2[t];
        for (int h = 0; h < 128; h++) v += t1[h] * Wr2[h * 3 + t];
        gsl[32 + t] = v;
    }
    __syncthreads();
    if (t == 0) {
        float v0 = gsl[32], v1 = gsl[33], v2 = gsl[34];
        float m = fmaxf(v0, fmaxf(v1, v2));
        float e0 = expf(v0 - m), e1 = expf(v1 - m), e2 = expf(v2 - m);
        float inv = 1.f / (e0 + e1 + e2);
        hdr[1] = e0 * inv; hdr[2] = e1 * inv; hdr[3] = e2 * inv;
        hdr[4] = 1.f + 0.5f * (hdr[0] * (1.f / (float)NN));
    }
}

// ---------------- Fused edge kernel: R17 structure (proven 308.6us) ----------------
// LDS pool (floats):
//   phase A: EIB[64][76] @0 (4864), WPan[2][12][128] @4864 (3072)  -> 7936
//   phase B: ehTh[64][68] @0 (4352), WgPan[3][16][64] @4352 (3072) -> 7424
//   phase C: Gbuf[64][68] @0 (4352)
//   persistent: rawS @7936 (64); pool = 8000 fl = 32000 B
#define EIB_S 76
__global__ __launch_bounds__(256) void edge_fused_kernel(
    const int* __restrict__ tgt_idx, const float* __restrict__ edge_attr,
    const float* __restrict__ x,
    const float* __restrict__ Ws1, const float* __restrict__ bs1,
    const float* __restrict__ ln_g, const float* __restrict__ ln_b,
    const float* __restrict__ Ws2, const float* __restrict__ bs2,
    const float* __restrict__ Wp, const float* __restrict__ bp,
    const float* __restrict__ Wg1, const float* __restrict__ bg1,
    const float* __restrict__ Wg2, const float* __restrict__ bg2,
    const float* __restrict__ PA1, const float* __restrict__ PA2,
    const float* __restrict__ hdr, float* __restrict__ scores)
{
    __shared__ float pool[8000];
    float* EIB   = pool;            // [64][76]
    float* WPan  = pool + 4864;     // [2][12][128]
    float* ehTh  = pool;            // [64 k-local][68]
    float* WgPan = pool + 4352;     // [3][16][64]
    float* Gbuf  = pool;            // [64 m][68]
    float* rawS  = pool + 7936;     // [64]

    int t = threadIdx.x;
    int e0 = blockIdx.x * 64;

    // ---- stage shifted edge input: local col ii <-> original k = 64+ii ----
    {
        int r = t >> 2, q = t & 3;
        int ge = e0 + r;
        int tg = tgt_idx[ge];
        #pragma unroll
        for (int i = 0; i < 4; i++) {
            int col = q * 16 + 4 * i;
            *(float4*)&EIB[r * EIB_S + col] = ld4(&x[tg * 64 + col]);
        }
        if (q == 0) {
            float4 v;
            v.x = edge_attr[(size_t)ge * 3 + 0];
            v.y = edge_attr[(size_t)ge * 3 + 1];
            v.z = edge_attr[(size_t)ge * 3 + 2];
            v.w = 0.f;
            *(float4*)&EIB[r * EIB_S + 64] = v;
        } else if (q == 1) {
            *(float4*)&EIB[r * EIB_S + 68] = make_float4(0.f, 0.f, 0.f, 0.f);
        } else if (q == 2) {
            *(float4*)&EIB[r * EIB_S + 72] = make_float4(0.f, 0.f, 0.f, 0.f);
        }
    }

    // ---- per-thread staging descriptors (t-only; hoisted out of the loops) ----
    // dual-GEMM panels: 3 float4 per thread
    int spr0, spc0, sdst0, spr1, spc1, sdst1, spr2, spc2, sdst2;
    const float *ssrc0, *ssrc1, *ssrc2;
    {
        int fid, mat, loc;
        fid = t;            mat = (fid >= 384) ? 1 : 0; loc = fid - mat * 384;
        spr0 = loc >> 5; spc0 = (loc & 31) * 4; sdst0 = mat * 1536 + spr0 * 128 + spc0;
        ssrc0 = mat ? Wp : Ws1;
        fid = 256 + t;      mat = (fid >= 384) ? 1 : 0; loc = fid - mat * 384;
        spr1 = loc >> 5; spc1 = (loc & 31) * 4; sdst1 = mat * 1536 + spr1 * 128 + spc1;
        ssrc1 = mat ? Wp : Ws1;
        fid = 512 + t;      mat = (fid >= 384) ? 1 : 0; loc = fid - mat * 384;
        spr2 = loc >> 5; spc2 = (loc & 31) * 4; sdst2 = mat * 1536 + spr2 * 128 + spc2;
        ssrc2 = mat ? Wp : Ws1;
    }
    // gating panels: 3 float4 per thread; src row(gi) = goff + gi*1024
    int gdst0, gdst1, gdst2, goff0, goff1, goff2;
    {
        int fid, rr, loc, pr, pc;
        fid = t;        rr = fid >> 8; loc = fid & 255; pr = loc >> 4; pc = (loc & 15) * 4;
        gdst0 = rr * 1024 + pr * 64 + pc; goff0 = rr * 8192 + pr * 64 + pc;
        fid = 256 + t;  rr = fid >> 8; loc = fid & 255; pr = loc >> 4; pc = (loc & 15) * 4;
        gdst1 = rr * 1024 + pr * 64 + pc; goff1 = rr * 8192 + pr * 64 + pc;
        fid = 512 + t;  rr = fid >> 8; loc = fid & 255; pr = loc >> 4; pc = (loc & 15) * 4;
        gdst2 = rr * 1024 + pr * 64 + pc; goff2 = rr * 8192 + pr * 64 + pc;
    }

    #define LOADP(pp, w0_, w1_, w2_)                                          \
      { int _pr0 = 64 + (pp) * 12 + spr0;                                     \
        int _pr1 = 64 + (pp) * 12 + spr1;                                     \
        int _pr2 = 64 + (pp) * 12 + spr2;                                     \
        w0_ = (_pr0 < 131) ? ld4(&ssrc0[_pr0 * 128 + spc0]) : make_float4(0.f,0.f,0.f,0.f); \
        w1_ = (_pr1 < 131) ? ld4(&ssrc1[_pr1 * 128 + spc1]) : make_float4(0.f,0.f,0.f,0.f); \
        w2_ = (_pr2 < 131) ? ld4(&ssrc2[_pr2 * 128 + spc2]) : make_float4(0.f,0.f,0.f,0.f); }

    #define LOADG(gi_, g0_, g1_, g2_)                                         \
      { g0_ = ld4(&Wg1[goff0 + (gi_) * 1024]);                                \
        g1_ = ld4(&Wg1[goff1 + (gi_) * 1024]);                                \
        g2_ = ld4(&Wg1[goff2 + (gi_) * 1024]); }

    int tcol = t & 7, trow = t >> 3;   // scalar col j: tcol*4 + (j>>2)*32 + (j&3); rows 2*trow,2*trow+1
    const float* EIr0 = &EIB[(2 * trow) * EIB_S];
    const float* EIr1 = EIr0 + EIB_S;
    int src = (e0 + 2 * trow) >> 5;

    v2f accs0[8], accs1[8], accp0[8], accp1[8];

    // ---- init accumulators from prefix tables (exact chain state after k=63) ----
    {
        const float* p1 = &PA1[(size_t)src * 128 + tcol * 4];
        const float* p2 = &PA2[(size_t)src * 128 + tcol * 4];
        #pragma unroll
        for (int jj = 0; jj < 4; jj++) {
            float4 v;
            v = ld4(p1 + jj * 32);
            v2f lo1 = { v.x, v.y }, hi1 = { v.z, v.w };
            accs0[jj*2] = lo1; accs0[jj*2+1] = hi1;
            accs1[jj*2] = lo1; accs1[jj*2+1] = hi1;
            v = ld4(p2 + jj * 32);
            v2f lo2 = { v.x, v.y }, hi2 = { v.z, v.w };
            accp0[jj*2] = lo2; accp0[jj*2+1] = hi2;
            accp1[jj*2] = lo2; accp1[jj*2+1] = hi2;
        }
    }

    // ---- fused dual-GEMM k-loop: 6 panels x 12 rows (original k = 64..135) ----
    float4 wra, wrb, wrc;
    LOADP(0, wra, wrb, wrc);                   // issued early; lands under EIB latency
    for (int p = 0; p < 6; p++) {
        __syncthreads();                       // prior panel reads done (p=0: nothing)
        *(float4*)&WPan[sdst0] = wra;
        *(float4*)&WPan[sdst1] = wrb;
        *(float4*)&WPan[sdst2] = wrc;
        if (p < 5) LOADP(p + 1, wra, wrb, wrc);   // hidden under this panel's compute
        __syncthreads();                       // WPan (and EIB at p=0) visible
        #pragma unroll
        for (int kk = 0; kk < 12; kk++) {
            int k = p * 12 + kk;
            float a0 = EIr0[k];
            float a1 = EIr1[k];
            v2f a0v = { a0, a0 }, a1v = { a1, a1 };
            const float* ws = &WPan[kk * 128 + tcol * 4];
            const float* wq = ws + 1536;
            #pragma unroll
            for (int jj = 0; jj < 4; jj++) {
                float4 w1 = ld4(ws + jj * 32);
                v2f w1a = { w1.x, w1.y }, w1b = { w1.z, w1.w };
                accs0[jj*2]   = PKFMA(a0v, w1a, accs0[jj*2]);
                accs0[jj*2+1] = PKFMA(a0v, w1b, accs0[jj*2+1]);
                accs1[jj*2]   = PKFMA(a1v, w1a, accs1[jj*2]);
                accs1[jj*2+1] = PKFMA(a1v, w1b, accs1[jj*2+1]);
                float4 w2 = ld4(wq + jj * 32);
                v2f w2a = { w2.x, w2.y }, w2b = { w2.z, w2.w };
                accp0[jj*2]   = PKFMA(a0v, w2a, accp0[jj*2]);
                accp0[jj*2+1] = PKFMA(a0v, w2b, accp0[jj*2+1]);
                accp1[jj*2]   = PKFMA(a1v, w2a, accp1[jj*2]);
                accp1[jj*2+1] = PKFMA(a1v, w2b, accp1[jj*2+1]);
            }
        }
    }

    // ---- prefetch first gating panel; lands under LN phase ----
    float4 gra, grb, grc;
    LOADG(0, gra, grb, grc);

    // ---- +bias, LayerNorm, LeakyReLU, dot Ws2 (verbatim scalar chains) ----
    {
        float s0 = 0.f, ss0 = 0.f, s1 = 0.f, ss1 = 0.f;
        #pragma unroll
        for (int j = 0; j < 16; j++) {
            int col = tcol * 4 + (j >> 2) * 32 + (j & 3);
            float b = bs1[col];
            float u0 = AIDX(accs0, j) + b;  AIDX(accs0, j) = u0;
            float u1 = AIDX(accs1, j) + b;  AIDX(accs1, j) = u1;
            s0 += u0; ss0 += u0 * u0;
            s1 += u1; ss1 += u1 * u1;
        }
        #pragma unroll
        for (int m = 1; m < 8; m <<= 1) {
            s0 += __shfl_xor(s0, m);  ss0 += __shfl_xor(ss0, m);
            s1 += __shfl_xor(s1, m);  ss1 += __shfl_xor(ss1, m);
        }
        float mu0 = s0 * (1.f / 128.f), mu1 = s1 * (1.f / 128.f);
        float var0 = ss0 * (1.f / 128.f) - mu0 * mu0;
        float var1 = ss1 * (1.f / 128.f) - mu1 * mu1;
        float inv0 = 1.f / sqrtf(var0 + EPS_LN);
        float inv1 = 1.f / sqrtf(var1 + EPS_LN);
        float d0 = 0.f, d1 = 0.f;
        #pragma unroll
        for (int j = 0; j < 16; j++) {
            int col = tcol * 4 + (j >> 2) * 32 + (j & 3);
            float g = ln_g[col], bb = ln_b[col], w2 = Ws2[col];
            float y0 = (AIDX(accs0, j) - mu0) * inv0 * g + bb;
            float y1 = (AIDX(accs1, j) - mu1) * inv1 * g + bb;
            y0 = (y0 >= 0.f) ? y0 : NEG_SLOPE * y0;
            y1 = (y1 >= 0.f) ? y1 : NEG_SLOPE * y1;
            d0 += y0 * w2; d1 += y1 * w2;
        }
        #pragma unroll
        for (int m = 1; m < 8; m <<= 1) {
            d0 += __shfl_xor(d0, m); d1 += __shfl_xor(d1, m);
        }
        if (tcol == 0) {
            rawS[2 * trow]     = d0 + bs2[0];
            rawS[2 * trow + 1] = d1 + bs2[0];
        }
    }

    // ================= gating: two 64-k halves of ehT, packed gacc persists =================
    int gtr = t >> 4, gtc = t & 15;            // edges 4*gtr+i ; m 4*gtc+j
    int grow = t >> 2, gq = t & 3;             // p-phase mapping (R1 chain)

    v2f gaccv[3][8];
    #pragma unroll
    for (int rr = 0; rr < 3; rr++)
        #pragma unroll
        for (int j = 0; j < 8; j++) gaccv[rr][j] = (v2f){ 0.f, 0.f };

    for (int hf = 0; hf < 2; hf++) {
        __syncthreads();                       // EIB/WPan (hf=0) or prior ehTh reads done
        #pragma unroll
        for (int j2 = 0; j2 < 8; j2++) {
            int j = hf * 8 + j2;
            int col = tcol * 4 + (j >> 2) * 32 + (j & 3);
            int lc = col - hf * 64;            // 0..63
            float b = bp[col];
            ehTh[lc * 68 + 2 * trow]     = fmaxf(AIDX(accp0, j) + b, 0.f);
            ehTh[lc * 68 + 2 * trow + 1] = fmaxf(AIDX(accp1, j) + b, 0.f);
        }
        for (int p = 0; p < 4; p++) {
            __syncthreads();                   // ehTh writes visible (p==0) / prior panel reads done
            *(float4*)&WgPan[gdst0] = gra;
            *(float4*)&WgPan[gdst1] = grb;
            *(float4*)&WgPan[gdst2] = grc;
            {
                int gi = hf * 4 + p;
                if (gi < 7) LOADG(gi + 1, gra, grb, grc);  // hidden under this panel's compute
            }
            __syncthreads();
            #pragma unroll
            for (int kk = 0; kk < 16; kk++) {
                float4 av = ld4(&ehTh[(p * 16 + kk) * 68 + 4 * gtr]);
                v2f ax = { av.x, av.x }, ay = { av.y, av.y };
                v2f az = { av.z, av.z }, aw = { av.w, av.w };
                #pragma unroll
                for (int rr = 0; rr < 3; rr++) {
                    float4 bv = ld4(&WgPan[rr * 1024 + kk * 64 + 4 * gtc]);
                    v2f bva = { bv.x, bv.y }, bvb = { bv.z, bv.w };
                    gaccv[rr][0] = PKFMA(ax, bva, gaccv[rr][0]);
                    gaccv[rr][1] = PKFMA(ax, bvb, gaccv[rr][1]);
                    gaccv[rr][2] = PKFMA(ay, bva, gaccv[rr][2]);
                    gaccv[rr][3] = PKFMA(ay, bvb, gaccv[rr][3]);
                    gaccv[rr][4] = PKFMA(az, bva, gaccv[rr][4]);
                    gaccv[rr][5] = PKFMA(az, bvb, gaccv[rr][5]);
                    gaccv[rr][6] = PKFMA(aw, bva, gaccv[rr][6]);
                    gaccv[rr][7] = PKFMA(aw, bvb, gaccv[rr][7]);
                }
            }
        }
    }

    // ---- Gbuf + p-phase per regime (R1 lane mapping / add order) ----
    float gc = 0.f;
    for (int rr = 0; rr < 3; rr++) {
        __syncthreads();                       // ehTh k-loop reads (rr==0) / prior p-phase reads done
        #pragma unroll
        for (int j = 0; j < 4; j++) {
            float b = bg1[rr * 64 + 4 * gtc + j];
            float4 g;
            g.x = fmaxf(GIDX(rr, 0  + j) + b, 0.f);
            g.y = fmaxf(GIDX(rr, 4  + j) + b, 0.f);
            g.z = fmaxf(GIDX(rr, 8  + j) + b, 0.f);
            g.w = fmaxf(GIDX(rr, 12 + j) + b, 0.f);
            *(float4*)&Gbuf[(4 * gtc + j) * 68 + 4 * gtr] = g;
        }
        __syncthreads();
        float pacc = 0.f;
        #pragma unroll
        for (int j = 0; j < 16; j++) {
            int m = gq * 4 + (j >> 2) * 16 + (j & 3);
            pacc += Gbuf[m * 68 + grow] * Wg2[rr * 64 + m];
        }
        pacc += __shfl_xor(pacc, 1);
        pacc += __shfl_xor(pacc, 2);
        float gate = 1.f / (1.f + expf(-(pacc + bg2[rr])));
        gc += gate * hdr[1 + rr];
    }
    if (gq == 0) scores[e0 + grow] = rawS[grow] * gc * hdr[4];
}

// ---------------- Kernel D: dedup + softmax + stable top-k, 2 rows per block ----------------
// Lanes 0..31 handle row 2*bid, lanes 32..63 handle row 2*bid+1. The original
// 64-wide xor reductions' mm=32 step only added +0.0f (sum) / fmax(x,-INF)
// (max) from the padding half -> dropping it is bit-identical.
__global__ __launch_bounds__(64) void finalize_kernel(
    const int* __restrict__ tgt_idx, const float* __restrict__ scores,
    float* __restrict__ out_w, float* __restrict__ out_i)
{
    __shared__ int   tl[64];
    __shared__ float pl[64];
    int j = threadIdx.x;
    int half = j >> 5;          // which row of the pair
    int jl = j & 31;            // lane within row
    int hb = half * 32;
    int row = blockIdx.x * 2 + half;
    int   tg = tgt_idx[row * 32 + jl];
    float s  = scores[row * 32 + jl];
    tl[j] = tg;
    __syncthreads();

    bool alive = true;
    for (int j2 = jl + 1; j2 < 32; j2++)
        if (tl[hb + j2] == tg) { alive = false; break; }
    float z = alive ? s * (1.f / TEMP) : -INFINITY;
    float m = z;
    #pragma unroll
    for (int mm = 1; mm < 32; mm <<= 1) m = fmaxf(m, __shfl_xor(m, mm));
    float p = alive ? expf(z - m) : 0.f;
    float sum = p;
    #pragma unroll
    for (int mm = 1; mm < 32; mm <<= 1) sum += __shfl_xor(sum, mm);
    p = p / sum;
    pl[j] = alive ? p : -1.f;
    __syncthreads();

    int rank = 0, dcount = 0;
    for (int j2 = 0; j2 < 32; j2++) {
        float pj = pl[hb + j2];
        if (pj >= 0.f) {
            dcount++;
            if (alive) {
                if (pj > p || (pj == p && tl[hb + j2] < tg)) rank++;
            }
        }
    }
    if (alive) {
        out_w[row * 32 + rank] = (p > W_THRESH) ? p : 0.f;
        out_i[row * 32 + rank] = (float)tg;
    }
    if (jl == 0) {
        int c = 0;
        for (int slot = dcount; slot < 32; slot++) {
            for (;;) {
                bool found = false;
                for (int q = 0; q < 32; q++) if (tl[hb + q] == c) { found = true; break; }
                if (!found) break;
                c++;
            }
            out_w[row * 32 + slot] = 0.f;
            out_i[row * 32 + slot] = (float)c;
            c++;
        }
    }
}

extern "C" void kernel_launch(void* const* d_in, const int* in_sizes, int n_in,
                              void* d_out, int out_size, void* d_ws, size_t ws_size,
                              hipStream_t stream)
{
    const float* x          = (const float*)d_in[0];
    const int*   edge_index = (const int*)  d_in[1];
    const float* edge_attr  = (const float*)d_in[2];
    const float* Ws1 = (const float*)d_in[3];
    const float* bs1 = (const float*)d_in[4];
    const float* ln_g = (const float*)d_in[5];
    const float* ln_b = (const float*)d_in[6];
    const float* Ws2 = (const float*)d_in[7];
    const float* bs2 = (const float*)d_in[8];
    const float* Wp  = (const float*)d_in[9];
    const float* bp  = (const float*)d_in[10];
    const float* Wr1 = (const float*)d_in[11];
    const float* br1 = (const float*)d_in[12];
    const float* Wr2 = (const float*)d_in[13];
    const float* br2 = (const float*)d_in[14];
    const float* Wg1 = (const float*)d_in[15];
    const float* bg1 = (const float*)d_in[16];
    const float* Wg2 = (const float*)d_in[17];
    const float* bg2 = (const float*)d_in[18];
    const float* Wc1 = (const float*)d_in[19];
    const float* bc1 = (const float*)d_in[20];
    const float* Wc2 = (const float*)d_in[21];
    const float* bc2 = (const float*)d_in[22];

    float* hdr    = (float*)d_ws;
    float* scores = hdr + 128;
    float* tabs   = scores + EE;            // PA1, PA2
    const int* tgt = edge_index + EE;       // row 1 of edge_index

    hipMemsetAsync(d_ws, 0, 512, stream);
    setup_kernel<<<1152, 256, 0, stream>>>(x, Ws1, Wp, Wc1, bc1, Wc2, bc2, tabs, hdr);
    regime_kernel<<<1, 128, 0, stream>>>(Wr1, br1, Wr2, br2, hdr);
    edge_fused_kernel<<<EE / 64, 256, 0, stream>>>(
        tgt, edge_attr, x, Ws1, bs1, ln_g, ln_b, Ws2, bs2, Wp, bp,
        Wg1, bg1, Wg2, bg2, tabs, tabs + (size_t)NN * 128, hdr, scores);
    finalize_kernel<<<NN / 2, 64, 0, stream>>>(
        tgt, scores, (float*)d_out, (float*)d_out + NN * KK);
}